// Round 1
// baseline (5654.929 us; speedup 1.0000x reference)
//
#include <hip/hip_runtime.h>
#include <math.h>

#define BATCH 1024
#define TSEQ  2048
#define DIN   5
#define H     64
#define NG    256   // 4*H gates
#define NOUT  128

__device__ __forceinline__ float sigmoid_fast(float x) {
    return 1.0f / (1.0f + __expf(-x));
}
__device__ __forceinline__ float tanh_fast(float x) {
    // tanh(x) = 1 - 2/(exp(2x)+1); stable at both tails
    return 1.0f - 2.0f / (__expf(2.0f * x) + 1.0f);
}

__global__ __launch_bounds__(256, 2)
void lstm_fused(const float* __restrict__ x,
                const float* __restrict__ Wih0, const float* __restrict__ Whh0,
                const float* __restrict__ bih0, const float* __restrict__ bhh0,
                const float* __restrict__ Wih1, const float* __restrict__ Whh1,
                const float* __restrict__ bih1, const float* __restrict__ bhh1,
                const float* __restrict__ Wfc,  const float* __restrict__ bfc,
                float* __restrict__ out)
{
    __shared__ float xs[TSEQ * DIN];   // 40 KB: whole input sequence for this batch elem
    __shared__ float h1s[H];
    __shared__ float h2s[H];
    __shared__ float gbuf[NG];

    const int tid = threadIdx.x;
    const int b   = blockIdx.x;

    // ---- preload x[b,:,:] (contiguous 10240 floats) into LDS, coalesced ----
    {
        const float4* src = (const float4*)(x + (size_t)b * TSEQ * DIN);
        float4* dst = (float4*)xs;
        #pragma unroll
        for (int i = 0; i < (TSEQ * DIN / 4) / 256; ++i)
            dst[i * 256 + tid] = src[i * 256 + tid];
    }
    if (tid < H) { h1s[tid] = 0.0f; h2s[tid] = 0.0f; }

    // ---- per-thread weight rows (registers) ----
    float wih0r[DIN];
    float whh0r[H];
    float wih1r[H];
    float whh1r[H];
    #pragma unroll
    for (int d = 0; d < DIN; ++d) wih0r[d] = Wih0[tid * DIN + d];
    #pragma unroll
    for (int j = 0; j < H; ++j)   whh0r[j] = Whh0[tid * H + j];
    #pragma unroll
    for (int j = 0; j < H; ++j)   wih1r[j] = Wih1[tid * H + j];
    #pragma unroll
    for (int j = 0; j < H; ++j)   whh1r[j] = Whh1[tid * H + j];
    const float bias0 = bih0[tid] + bhh0[tid];
    const float bias1 = bih1[tid] + bhh1[tid];

    float c1 = 0.0f, c2 = 0.0f;          // cell state: owned by threads 0..63
    const int sel = tid >> 6;            // 0:i 1:f 2:g 3:o  (wave-uniform)

    __syncthreads();

    for (int t = 0; t < TSEQ; ++t) {
        // ================= layer 1 gates =================
        float a0 = bias0, a1 = 0.0f, a2 = 0.0f, a3 = 0.0f;
        {
            const float* xt = xs + t * DIN;
            a0 = fmaf(xt[0], wih0r[0], a0);
            a1 = fmaf(xt[1], wih0r[1], a1);
            a2 = fmaf(xt[2], wih0r[2], a2);
            a3 = fmaf(xt[3], wih0r[3], a3);
            a0 = fmaf(xt[4], wih0r[4], a0);
        }
        {
            const float4* h4 = (const float4*)h1s;
            #pragma unroll
            for (int k = 0; k < H / 4; ++k) {
                float4 hv = h4[k];
                a0 = fmaf(hv.x, whh0r[4*k+0], a0);
                a1 = fmaf(hv.y, whh0r[4*k+1], a1);
                a2 = fmaf(hv.z, whh0r[4*k+2], a2);
                a3 = fmaf(hv.w, whh0r[4*k+3], a3);
            }
        }
        float a = (a0 + a1) + (a2 + a3);
        gbuf[tid] = (sel == 2) ? tanh_fast(a) : sigmoid_fast(a);
        __syncthreads();                                   // B1: gbuf ready
        if (tid < H) {
            float iv = gbuf[tid], fv = gbuf[H + tid];
            float gv = gbuf[2*H + tid], ov = gbuf[3*H + tid];
            c1 = fmaf(fv, c1, iv * gv);
            h1s[tid] = ov * tanh_fast(c1);
        }
        __syncthreads();                                   // B2: h1s (=y1_t) ready

        // ================= layer 2 gates =================
        float b0 = bias1, b1 = 0.0f, b2 = 0.0f, b3 = 0.0f;
        {
            const float4* y4 = (const float4*)h1s;
            #pragma unroll
            for (int k = 0; k < H / 4; ++k) {
                float4 yv = y4[k];
                b0 = fmaf(yv.x, wih1r[4*k+0], b0);
                b1 = fmaf(yv.y, wih1r[4*k+1], b1);
                b2 = fmaf(yv.z, wih1r[4*k+2], b2);
                b3 = fmaf(yv.w, wih1r[4*k+3], b3);
            }
        }
        {
            const float4* h4 = (const float4*)h2s;
            #pragma unroll
            for (int k = 0; k < H / 4; ++k) {
                float4 hv = h4[k];
                b0 = fmaf(hv.x, whh1r[4*k+0], b0);
                b1 = fmaf(hv.y, whh1r[4*k+1], b1);
                b2 = fmaf(hv.z, whh1r[4*k+2], b2);
                b3 = fmaf(hv.w, whh1r[4*k+3], b3);
            }
        }
        float bb = (b0 + b1) + (b2 + b3);
        gbuf[tid] = (sel == 2) ? tanh_fast(bb) : sigmoid_fast(bb);
        __syncthreads();                                   // B3: gbuf ready
        if (tid < H) {
            float iv = gbuf[tid], fv = gbuf[H + tid];
            float gv = gbuf[2*H + tid], ov = gbuf[3*H + tid];
            c2 = fmaf(fv, c2, iv * gv);
            h2s[tid] = ov * tanh_fast(c2);
        }
        __syncthreads();                                   // B4: h2s ready for t+1
    }

    // ---- final FC on h2(T-1): out[b,o] = relu(bfc[o] + sum_j h2[j]*Wfc[o,j]) ----
    if (tid < NOUT) {
        float s0 = 0.0f, s1 = 0.0f, s2 = 0.0f, s3 = 0.0f;
        const float4* w4 = (const float4*)(Wfc + tid * H);
        const float4* h4 = (const float4*)h2s;
        #pragma unroll
        for (int k = 0; k < H / 4; ++k) {
            float4 wv = w4[k]; float4 hv = h4[k];
            s0 = fmaf(wv.x, hv.x, s0);
            s1 = fmaf(wv.y, hv.y, s1);
            s2 = fmaf(wv.z, hv.z, s2);
            s3 = fmaf(wv.w, hv.w, s3);
        }
        float acc = bfc[tid] + (s0 + s1) + (s2 + s3);
        out[(size_t)b * NOUT + tid] = fmaxf(acc, 0.0f);
    }
}

extern "C" void kernel_launch(void* const* d_in, const int* in_sizes, int n_in,
                              void* d_out, int out_size, void* d_ws, size_t ws_size,
                              hipStream_t stream) {
    const float* x    = (const float*)d_in[0];
    const float* Wih0 = (const float*)d_in[1];
    const float* Whh0 = (const float*)d_in[2];
    const float* bih0 = (const float*)d_in[3];
    const float* bhh0 = (const float*)d_in[4];
    const float* Wih1 = (const float*)d_in[5];
    const float* Whh1 = (const float*)d_in[6];
    const float* bih1 = (const float*)d_in[7];
    const float* bhh1 = (const float*)d_in[8];
    const float* Wfc  = (const float*)d_in[9];
    const float* bfc  = (const float*)d_in[10];
    float* out = (float*)d_out;

    lstm_fused<<<dim3(BATCH), dim3(256), 0, stream>>>(
        x, Wih0, Whh0, bih0, bhh0, Wih1, Whh1, bih1, bhh1, Wfc, bfc, out);
}

// Round 2
// 3837.503 us; speedup vs baseline: 1.4736x; 1.4736x over previous
//
#include <hip/hip_runtime.h>
#include <math.h>

#define BATCH 1024
#define TSEQ  2048
#define DIN   5
#define DINP  6      // padded to even for half2
#define H     64
#define NG    256    // 4*H gates
#define NOUT  128

typedef _Float16 half2 __attribute__((ext_vector_type(2)));

#if __has_builtin(__builtin_amdgcn_fdot2)
__device__ __forceinline__ float FDOT2(half2 a, half2 b, float c) {
    return __builtin_amdgcn_fdot2(a, b, c, false);
}
#else
__device__ __forceinline__ float FDOT2(half2 a, half2 b, float c) {
    return fmaf((float)a.x, (float)b.x, fmaf((float)a.y, (float)b.y, c));
}
#endif

__device__ __forceinline__ float sigmoid_fast(float x) {
    return 1.0f / (1.0f + __expf(-x));
}
__device__ __forceinline__ float tanh_fast(float x) {
    return 1.0f - 2.0f / (__expf(2.0f * x) + 1.0f);
}

// 2 batch elements per block; thread g owns gate row g for BOTH elements
// (weight registers shared). Gate dot products use v_dot2_f32_f16 (2 MAC/inst,
// fp32 accumulate). 512 blocks = 2 blocks/CU exactly, one pass.
__global__ __launch_bounds__(256) __attribute__((amdgpu_waves_per_eu(2, 2)))
void lstm_fused(const float* __restrict__ x,
                const float* __restrict__ Wih0, const float* __restrict__ Whh0,
                const float* __restrict__ bih0, const float* __restrict__ bhh0,
                const float* __restrict__ Wih1, const float* __restrict__ Whh1,
                const float* __restrict__ bih1, const float* __restrict__ bhh1,
                const float* __restrict__ Wfc,  const float* __restrict__ bfc,
                float* __restrict__ out)
{
    __shared__ alignas(16) _Float16 xs[2][TSEQ * DINP];  // 48 KB: fp16 input, padded stride 6
    __shared__ alignas(16) float    gbuf[2][NG];         // 2 KB gate activations
    __shared__ alignas(16) _Float16 hbuf1[2][H];         // h1 (fp16 for dot2)
    __shared__ alignas(16) _Float16 hbuf2[2][H];         // h2 (fp16 for dot2)
    __shared__ alignas(16) float    h2f[2][H];           // h2 in fp32 (for FC epilogue)

    const int tid = threadIdx.x;
    const int uw  = tid >> 6;   // wave id 0..3 (also gate-type selector)
    const int ul  = tid & 63;

    const int b0 = 2 * blockIdx.x;

    // ---- preload x for both elems, fp32 -> fp16, re-stride 5 -> 6 ----
    #pragma unroll
    for (int e = 0; e < 2; ++e) {
        const float* xb = x + (size_t)(b0 + e) * TSEQ * DIN;
        for (int idx = tid; idx < TSEQ * DIN; idx += 256) {
            int t = idx / DIN;
            int d = idx - t * DIN;
            xs[e][t * DINP + d] = (_Float16)xb[idx];
        }
        for (int t = tid; t < TSEQ; t += 256)
            xs[e][t * DINP + DIN] = (_Float16)0.0f;
    }
    if (tid < H) {
        hbuf1[0][tid] = (_Float16)0.0f; hbuf1[1][tid] = (_Float16)0.0f;
        hbuf2[0][tid] = (_Float16)0.0f; hbuf2[1][tid] = (_Float16)0.0f;
    }

    // ---- per-thread packed fp16 weight rows (registers, shared by both elems) ----
    half2 wx0[DINP / 2];  // Wih0 row, padded
    half2 wh0[H / 2];     // Whh0 row
    half2 wi1[H / 2];     // Wih1 row
    half2 wh1[H / 2];     // Whh1 row
    {
        const float* r = Wih0 + tid * DIN;
        wx0[0] = half2{(_Float16)r[0], (_Float16)r[1]};
        wx0[1] = half2{(_Float16)r[2], (_Float16)r[3]};
        wx0[2] = half2{(_Float16)r[4], (_Float16)0.0f};
    }
    #pragma unroll
    for (int k = 0; k < H / 2; ++k) {
        wh0[k] = half2{(_Float16)Whh0[tid * H + 2*k], (_Float16)Whh0[tid * H + 2*k + 1]};
    }
    #pragma unroll
    for (int k = 0; k < H / 2; ++k) {
        wi1[k] = half2{(_Float16)Wih1[tid * H + 2*k], (_Float16)Wih1[tid * H + 2*k + 1]};
    }
    #pragma unroll
    for (int k = 0; k < H / 2; ++k) {
        wh1[k] = half2{(_Float16)Whh1[tid * H + 2*k], (_Float16)Whh1[tid * H + 2*k + 1]};
    }
    const float bias0 = bih0[tid] + bhh0[tid];
    const float bias1 = bih1[tid] + bhh1[tid];

    // cell state: wave 0 lanes own elem 0, wave 1 lanes own elem 1
    float c1 = 0.0f, c2 = 0.0f;

    __syncthreads();

    for (int t = 0; t < TSEQ; ++t) {
        // ================= layer 1 gates (both elems) =================
        {
            float A0[4] = {bias0, 0.0f, 0.0f, 0.0f};
            float A1[4] = {bias0, 0.0f, 0.0f, 0.0f};
            const half2* xt0 = (const half2*)(xs[0] + t * DINP);
            const half2* xt1 = (const half2*)(xs[1] + t * DINP);
            #pragma unroll
            for (int k = 0; k < DINP / 2; ++k) {
                A0[k] = FDOT2(xt0[k], wx0[k], A0[k]);
                A1[k] = FDOT2(xt1[k], wx0[k], A1[k]);
            }
            const half2* h10 = (const half2*)hbuf1[0];
            const half2* h11 = (const half2*)hbuf1[1];
            #pragma unroll
            for (int k = 0; k < H / 2; ++k) {
                A0[k & 3] = FDOT2(h10[k], wh0[k], A0[k & 3]);
                A1[k & 3] = FDOT2(h11[k], wh0[k], A1[k & 3]);
            }
            float a0 = (A0[0] + A0[1]) + (A0[2] + A0[3]);
            float a1 = (A1[0] + A1[1]) + (A1[2] + A1[3]);
            gbuf[0][tid] = (uw == 2) ? tanh_fast(a0) : sigmoid_fast(a0);
            gbuf[1][tid] = (uw == 2) ? tanh_fast(a1) : sigmoid_fast(a1);
        }
        __syncthreads();                                  // B1: layer-1 gates ready
        if (uw < 2) {                                     // wave e updates elem e
            const int e = uw;
            float iv = gbuf[e][ul],       fv = gbuf[e][H + ul];
            float gv = gbuf[e][2*H + ul], ov = gbuf[e][3*H + ul];
            c1 = fmaf(fv, c1, iv * gv);
            hbuf1[e][ul] = (_Float16)(ov * tanh_fast(c1));
        }
        __syncthreads();                                  // B2: h1 (=y1_t) ready

        // ================= layer 2 gates (both elems) =================
        {
            float B0[4] = {bias1, 0.0f, 0.0f, 0.0f};
            float B1v[4] = {bias1, 0.0f, 0.0f, 0.0f};
            const half2* y0 = (const half2*)hbuf1[0];
            const half2* y1 = (const half2*)hbuf1[1];
            const half2* h20 = (const half2*)hbuf2[0];
            const half2* h21 = (const half2*)hbuf2[1];
            #pragma unroll
            for (int k = 0; k < H / 2; ++k) {
                B0[k & 3]  = FDOT2(y0[k], wi1[k], B0[k & 3]);
                B1v[k & 3] = FDOT2(y1[k], wi1[k], B1v[k & 3]);
            }
            #pragma unroll
            for (int k = 0; k < H / 2; ++k) {
                B0[k & 3]  = FDOT2(h20[k], wh1[k], B0[k & 3]);
                B1v[k & 3] = FDOT2(h21[k], wh1[k], B1v[k & 3]);
            }
            float bA = (B0[0] + B0[1]) + (B0[2] + B0[3]);
            float bB = (B1v[0] + B1v[1]) + (B1v[2] + B1v[3]);
            gbuf[0][tid] = (uw == 2) ? tanh_fast(bA) : sigmoid_fast(bA);
            gbuf[1][tid] = (uw == 2) ? tanh_fast(bB) : sigmoid_fast(bB);
        }
        __syncthreads();                                  // B3: layer-2 gates ready
        if (uw < 2) {
            const int e = uw;
            float iv = gbuf[e][ul],       fv = gbuf[e][H + ul];
            float gv = gbuf[e][2*H + ul], ov = gbuf[e][3*H + ul];
            c2 = fmaf(fv, c2, iv * gv);
            float h = ov * tanh_fast(c2);
            hbuf2[e][ul] = (_Float16)h;
            h2f[e][ul] = h;                               // fp32 copy for FC
        }
        __syncthreads();                                  // B4: h2 ready for t+1
    }

    // ---- final FC on h2(T-1), fp32: thread -> (elem, out-row) ----
    {
        const int e = tid >> 7;          // 0 or 1
        const int o = tid & (NOUT - 1);  // 0..127
        float s0 = 0.0f, s1 = 0.0f, s2 = 0.0f, s3 = 0.0f;
        const float4* w4 = (const float4*)(Wfc + o * H);
        const float4* h4 = (const float4*)h2f[e];
        #pragma unroll
        for (int k = 0; k < H / 4; ++k) {
            float4 wv = w4[k]; float4 hv = h4[k];
            s0 = fmaf(wv.x, hv.x, s0);
            s1 = fmaf(wv.y, hv.y, s1);
            s2 = fmaf(wv.z, hv.z, s2);
            s3 = fmaf(wv.w, hv.w, s3);
        }
        float acc = bfc[o] + (s0 + s1) + (s2 + s3);
        out[(size_t)(b0 + e) * NOUT + o] = fmaxf(acc, 0.0f);
    }
}

extern "C" void kernel_launch(void* const* d_in, const int* in_sizes, int n_in,
                              void* d_out, int out_size, void* d_ws, size_t ws_size,
                              hipStream_t stream) {
    const float* x    = (const float*)d_in[0];
    const float* Wih0 = (const float*)d_in[1];
    const float* Whh0 = (const float*)d_in[2];
    const float* bih0 = (const float*)d_in[3];
    const float* bhh0 = (const float*)d_in[4];
    const float* Wih1 = (const float*)d_in[5];
    const float* Whh1 = (const float*)d_in[6];
    const float* bih1 = (const float*)d_in[7];
    const float* bhh1 = (const float*)d_in[8];
    const float* Wfc  = (const float*)d_in[9];
    const float* bfc  = (const float*)d_in[10];
    float* out = (float*)d_out;

    lstm_fused<<<dim3(BATCH / 2), dim3(256), 0, stream>>>(
        x, Wih0, Whh0, bih0, bhh0, Wih1, Whh1, bih1, bhh1, Wfc, bfc, out);
}

// Round 3
// 1987.038 us; speedup vs baseline: 2.8459x; 1.9313x over previous
//
#include <hip/hip_runtime.h>
#include <math.h>

#define BATCH  1024
#define TSEQ   2048
#define DIN    5
#define XSTR   6      // xs stride in halves (pad 5->6 for half2 alignment)
#define H      64
#define BT     4      // batch elems per block
#define RAWSTR 272    // raw gate buffer per-elem stride in words (16B-aligned, odd/16 to spread banks)
#define NOUT   128

typedef _Float16 f16x8  __attribute__((ext_vector_type(8)));
typedef _Float16 half2v __attribute__((ext_vector_type(2)));
typedef float    f32x4  __attribute__((ext_vector_type(4)));

#if __has_builtin(__builtin_amdgcn_fdot2)
__device__ __forceinline__ float FDOT2(half2v a, half2v b, float c) {
    return __builtin_amdgcn_fdot2(a, b, c, false);
}
#else
__device__ __forceinline__ float FDOT2(half2v a, half2v b, float c) {
    return fmaf((float)a.x, (float)b.x, fmaf((float)a.y, (float)b.y, c));
}
#endif

__device__ __forceinline__ float sigmoid_fast(float x) {
    return 1.0f / (1.0f + __expf(-x));
}
__device__ __forceinline__ float tanh_fast(float x) {
    // stable at both tails: exp(+-inf) handled -> +-1
    return 1.0f - 2.0f / (__expf(2.0f * x) + 1.0f);
}

// XOR-swizzled B-operand buffer: logical [n<16][k<128] fp16, 8-half groups
// swizzled by n so mfma B-fragment ds_read_b128 is 2-way-conflict-free.
__device__ __forceinline__ int b2idx(int n, int k) {
    return n * 128 + ((((k >> 3) ^ (n & 7)) << 3) | (k & 7));
}

// One block = 4 batch elems, 256 threads = 4 waves, 1 block/CU (grid 256).
// Wave w owns gate-type w (rows 64w..64w+63) as MFMA A-fragments (registers).
// 2-barrier software-pipelined loop: M = mfma[layer2(t) + layer1(t+1)],
// G = activations + c/h updates for both layers (thread (hu,e), no wasted lanes).
__global__ __launch_bounds__(256)
void lstm_mfma(const float* __restrict__ x,
               const float* __restrict__ Wih0, const float* __restrict__ Whh0,
               const float* __restrict__ bih0, const float* __restrict__ bhh0,
               const float* __restrict__ Wih1, const float* __restrict__ Whh1,
               const float* __restrict__ bih1, const float* __restrict__ bhh1,
               const float* __restrict__ Wfc,  const float* __restrict__ bfc,
               float* __restrict__ out)
{
    __shared__ alignas(16) _Float16 xs[BT][TSEQ * XSTR];   // 96 KB fp16 input
    __shared__ alignas(16) _Float16 b2B[16 * 128];         // 4 KB: B = [y1(64) ; h2(64)], swizzled
    __shared__ alignas(16) float    raw1[BT * RAWSTR];     // layer-1 mfma pre-activations
    __shared__ alignas(16) float    raw2[BT * RAWSTR];     // layer-2 mfma pre-activations
    __shared__ alignas(16) float    h2f[BT][H];            // final h2 for FC

    const int tid = threadIdx.x;
    const int w   = tid >> 6;          // wave id = gate-type (M) = elem (G)
    const int q   = (tid >> 4) & 3;    // quad within wave
    const int m   = tid & 15;          // A-row / D-col within tile
    const int hu  = tid & 63;          // h-unit owned in G phase
    const int e   = w;                 // elem owned in G phase
    const int b0  = blockIdx.x * BT;

    // ---------------- prologue: stage x (fp32 -> fp16, stride 5 -> 6) ----------------
    for (int el = 0; el < BT; ++el) {
        const float* xb = x + (size_t)(b0 + el) * TSEQ * DIN;
        for (int idx = tid; idx < TSEQ * DIN; idx += 256) {
            int t = idx / DIN;
            int d = idx - t * DIN;
            xs[el][t * XSTR + d] = (_Float16)xb[idx];
        }
        for (int t = tid; t < TSEQ; t += 256)
            xs[el][t * XSTR + DIN] = (_Float16)0.0f;
    }
    for (int j = tid; j < 16 * 128; j += 256) b2B[j] = (_Float16)0.0f;

    // ---------------- A-fragments (weights, resident in registers) ----------------
    // A[m=lane&15][k=q*8+j] ; layer-1 A = Whh0 (K=64), layer-2 A = [Wih1 | Whh1] (K=128)
    f16x8 a1[4][2];
    f16x8 a2[4][4];
    #pragma unroll
    for (int mt = 0; mt < 4; ++mt) {
        const int g = 64 * w + 16 * mt + m;
        #pragma unroll
        for (int kt = 0; kt < 2; ++kt) {
            const float* p = Whh0 + g * H + kt * 32 + q * 8;
            f16x8 f;
            #pragma unroll
            for (int j = 0; j < 8; ++j) f[j] = (_Float16)p[j];
            a1[mt][kt] = f;
        }
        #pragma unroll
        for (int kt = 0; kt < 2; ++kt) {
            const float* p = Wih1 + g * H + kt * 32 + q * 8;
            f16x8 f;
            #pragma unroll
            for (int j = 0; j < 8; ++j) f[j] = (_Float16)p[j];
            a2[mt][kt] = f;
        }
        #pragma unroll
        for (int kt = 0; kt < 2; ++kt) {
            const float* p = Whh1 + g * H + kt * 32 + q * 8;
            f16x8 f;
            #pragma unroll
            for (int j = 0; j < 8; ++j) f[j] = (_Float16)p[j];
            a2[mt][2 + kt] = f;
        }
    }

    // ---------------- G-phase weights: Wih0 rows {hu,64+hu,128+hu,192+hu} ----------------
    half2v w0x[4][3];
    float  bias0g[4], bias1g[4];
    #pragma unroll
    for (int gt = 0; gt < 4; ++gt) {
        const int g = gt * 64 + hu;
        const float* r = Wih0 + g * DIN;
        w0x[gt][0] = half2v{(_Float16)r[0], (_Float16)r[1]};
        w0x[gt][1] = half2v{(_Float16)r[2], (_Float16)r[3]};
        w0x[gt][2] = half2v{(_Float16)r[4], (_Float16)0.0f};
        bias0g[gt] = bih0[g] + bhh0[g];
        bias1g[gt] = bih1[g] + bhh1[g];
    }

    float c1 = 0.0f, c2 = 0.0f, h2fin = 0.0f;
    const f32x4 zz = {0.0f, 0.0f, 0.0f, 0.0f};

    __syncthreads();

    // ================= main loop: iteration i does layer2(t=i-1) + layer1(t=i) =================
    #pragma unroll 1
    for (int i = 0; i <= TSEQ; ++i) {
        // ---- M phase: B-fragments + 24 mfma + raw writeback ----
        f16x8 bf[4];
        #pragma unroll
        for (int kt = 0; kt < 4; ++kt)
            bf[kt] = *(const f16x8*)&b2B[b2idx(m, kt * 32 + q * 8)];

        f32x4 d1[4], d2[4];
        #pragma unroll
        for (int mt = 0; mt < 4; ++mt) {
            d1[mt] = __builtin_amdgcn_mfma_f32_16x16x32_f16(a1[mt][0], bf[0], zz, 0, 0, 0);
            d1[mt] = __builtin_amdgcn_mfma_f32_16x16x32_f16(a1[mt][1], bf[1], d1[mt], 0, 0, 0);
            d2[mt] = __builtin_amdgcn_mfma_f32_16x16x32_f16(a2[mt][0], bf[0], zz, 0, 0, 0);
            #pragma unroll
            for (int kt = 1; kt < 4; ++kt)
                d2[mt] = __builtin_amdgcn_mfma_f32_16x16x32_f16(a2[mt][kt], bf[kt], d2[mt], 0, 0, 0);
        }
        if (m < BT) {   // D col = lane&15 = elem; rows 16mt+4q+reg contiguous -> b128 stores
            #pragma unroll
            for (int mt = 0; mt < 4; ++mt) {
                *(f32x4*)&raw1[(64 * w + 16 * mt + 4 * q) + m * RAWSTR] = d1[mt];
                *(f32x4*)&raw2[(64 * w + 16 * mt + 4 * q) + m * RAWSTR] = d2[mt];
            }
        }
        __syncthreads();

        // ---- G phase: thread (hu, e) ----
        if (i < TSEQ) {
            // layer-1 gates for t=i : xp (K=5, fdot2) + raw1 + activation + c1/h1
            const half2v* xv = (const half2v*)&xs[e][i * XSTR];
            half2v xa = xv[0], xb = xv[1], xc = xv[2];
            float p0 = FDOT2(xc, w0x[0][2], FDOT2(xb, w0x[0][1], FDOT2(xa, w0x[0][0], bias0g[0])));
            float p1 = FDOT2(xc, w0x[1][2], FDOT2(xb, w0x[1][1], FDOT2(xa, w0x[1][0], bias0g[1])));
            float p2 = FDOT2(xc, w0x[2][2], FDOT2(xb, w0x[2][1], FDOT2(xa, w0x[2][0], bias0g[2])));
            float p3 = FDOT2(xc, w0x[3][2], FDOT2(xb, w0x[3][1], FDOT2(xa, w0x[3][0], bias0g[3])));
            p0 += raw1[hu       + e * RAWSTR];
            p1 += raw1[64 + hu  + e * RAWSTR];
            p2 += raw1[128 + hu + e * RAWSTR];
            p3 += raw1[192 + hu + e * RAWSTR];
            float iv = sigmoid_fast(p0);
            float fv = sigmoid_fast(p1);
            float gv = tanh_fast(p2);
            float ov = sigmoid_fast(p3);
            c1 = fmaf(fv, c1, iv * gv);
            b2B[b2idx(e, hu)] = (_Float16)(ov * tanh_fast(c1));
        }
        if (i > 0) {
            // layer-2 gates for t=i-1 : raw2 + bias + activation + c2/h2
            float q0 = bias1g[0] + raw2[hu       + e * RAWSTR];
            float q1 = bias1g[1] + raw2[64 + hu  + e * RAWSTR];
            float q2 = bias1g[2] + raw2[128 + hu + e * RAWSTR];
            float q3 = bias1g[3] + raw2[192 + hu + e * RAWSTR];
            float iv = sigmoid_fast(q0);
            float fv = sigmoid_fast(q1);
            float gv = tanh_fast(q2);
            float ov = sigmoid_fast(q3);
            c2 = fmaf(fv, c2, iv * gv);
            h2fin = ov * tanh_fast(c2);
            b2B[b2idx(e, 64 + hu)] = (_Float16)h2fin;
        }
        __syncthreads();
    }

    // ---------------- epilogue: out = relu(h2(T-1) @ Wfc^T + bfc) ----------------
    h2f[e][hu] = h2fin;
    __syncthreads();
    {
        const int o  = tid & (NOUT - 1);
        const int eb = (tid >> 7) * 2;
        #pragma unroll
        for (int rep = 0; rep < 2; ++rep) {
            const int ee = eb + rep;
            const float4* wr = (const float4*)(Wfc + o * H);
            const float*  hv = h2f[ee];
            float s0 = 0.0f, s1 = 0.0f, s2 = 0.0f, s3 = 0.0f;
            #pragma unroll
            for (int k = 0; k < H / 4; ++k) {
                float4 wv = wr[k];
                s0 = fmaf(wv.x, hv[4 * k + 0], s0);
                s1 = fmaf(wv.y, hv[4 * k + 1], s1);
                s2 = fmaf(wv.z, hv[4 * k + 2], s2);
                s3 = fmaf(wv.w, hv[4 * k + 3], s3);
            }
            float acc = bfc[o] + (s0 + s1) + (s2 + s3);
            out[(size_t)(b0 + ee) * NOUT + o] = fmaxf(acc, 0.0f);
        }
    }
}

extern "C" void kernel_launch(void* const* d_in, const int* in_sizes, int n_in,
                              void* d_out, int out_size, void* d_ws, size_t ws_size,
                              hipStream_t stream) {
    const float* x    = (const float*)d_in[0];
    const float* Wih0 = (const float*)d_in[1];
    const float* Whh0 = (const float*)d_in[2];
    const float* bih0 = (const float*)d_in[3];
    const float* bhh0 = (const float*)d_in[4];
    const float* Wih1 = (const float*)d_in[5];
    const float* Whh1 = (const float*)d_in[6];
    const float* bih1 = (const float*)d_in[7];
    const float* bhh1 = (const float*)d_in[8];
    const float* Wfc  = (const float*)d_in[9];
    const float* bfc  = (const float*)d_in[10];
    float* out = (float*)d_out;

    lstm_mfma<<<dim3(BATCH / BT), dim3(256), 0, stream>>>(
        x, Wih0, Whh0, bih0, bhh0, Wih1, Whh1, bih1, bhh1, Wfc, bfc, out);
}

// Round 4
// 1744.220 us; speedup vs baseline: 3.2421x; 1.1392x over previous
//
#include <hip/hip_runtime.h>
#include <math.h>

#define BATCH  1024
#define TSEQ   2048
#define DIN    5
#define XSTR   6      // xs stride in halves (pad 5->6 for half2 alignment)
#define H      64
#define BT     2      // batch elems per block -> grid 512 = 2 blocks/CU
#define RAWSTR 272    // raw gate buffer per-elem stride in words
#define NOUT   128

typedef _Float16 f16x8  __attribute__((ext_vector_type(8)));
typedef _Float16 half2v __attribute__((ext_vector_type(2)));
typedef float    f32x4  __attribute__((ext_vector_type(4)));

#if __has_builtin(__builtin_amdgcn_fdot2)
__device__ __forceinline__ float FDOT2(half2v a, half2v b, float c) {
    return __builtin_amdgcn_fdot2(a, b, c, false);
}
#else
__device__ __forceinline__ float FDOT2(half2v a, half2v b, float c) {
    return fmaf((float)a.x, (float)b.x, fmaf((float)a.y, (float)b.y, c));
}
#endif

#if __has_builtin(__builtin_amdgcn_rcpf)
__device__ __forceinline__ float rcp_fast(float x) { return __builtin_amdgcn_rcpf(x); }
#else
__device__ __forceinline__ float rcp_fast(float x) { return 1.0f / x; }
#endif

__device__ __forceinline__ float sigmoid_fast(float x) {
    return rcp_fast(1.0f + __expf(-x));          // v_exp + v_rcp, no IEEE div sequence
}
__device__ __forceinline__ float tanh_fast(float x) {
    return 1.0f - 2.0f * rcp_fast(__expf(2.0f * x) + 1.0f);
}

// XOR-swizzled B-operand buffer: logical [n<16][k<128] fp16, 8-half groups
// swizzled by n so mfma B-fragment ds_read_b128 is balanced across banks.
__device__ __forceinline__ int b2idx(int n, int k) {
    return n * 128 + ((((k >> 3) ^ (n & 7)) << 3) | (k & 7));
}

// Block = 2 batch elems, 256 threads = 4 waves; grid 512 = 2 blocks/CU.
// M phase: wave w owns gate-type w as resident MFMA A-fragments; 24 mfma/wave
// computing layer-1(t=i) and layer-2(t=i-1) pre-activations for both elems.
// G phase (wave-specialized): waves 0-1 = layer-1 update for elems 0,1;
// waves 2-3 = layer-2 update for elems 0,1.
__global__ __launch_bounds__(256)
void lstm_mfma(const float* __restrict__ x,
               const float* __restrict__ Wih0, const float* __restrict__ Whh0,
               const float* __restrict__ bih0, const float* __restrict__ bhh0,
               const float* __restrict__ Wih1, const float* __restrict__ Whh1,
               const float* __restrict__ bih1, const float* __restrict__ bhh1,
               const float* __restrict__ Wfc,  const float* __restrict__ bfc,
               float* __restrict__ out)
{
    __shared__ alignas(16) _Float16 xs[BT][TSEQ * XSTR];   // 48 KB fp16 input
    __shared__ alignas(16) _Float16 b2B[16 * 128];         // 4 KB: B = [y1(64) ; h2(64)], swizzled
    __shared__ alignas(16) float    raw1[BT * RAWSTR];     // layer-1 mfma pre-activations
    __shared__ alignas(16) float    raw2[BT * RAWSTR];     // layer-2 mfma pre-activations
    __shared__ alignas(16) float    h2f[BT][H];            // final h2 for FC

    const int tid = threadIdx.x;
    const int w   = tid >> 6;          // wave id: M gate-type; G (layer, elem)
    const int q   = (tid >> 4) & 3;    // quad within wave
    const int m   = tid & 15;          // A-row / D-col within tile
    const int hu  = tid & 63;          // h-unit owned in G phase
    const int b0  = blockIdx.x * BT;

    // ---------------- prologue: stage x (fp32 -> fp16, stride 5 -> 6) ----------------
    for (int el = 0; el < BT; ++el) {
        const float* xb = x + (size_t)(b0 + el) * TSEQ * DIN;
        for (int idx = tid; idx < TSEQ * DIN; idx += 256) {
            int t = idx / DIN;
            int d = idx - t * DIN;
            xs[el][t * XSTR + d] = (_Float16)xb[idx];
        }
        for (int t = tid; t < TSEQ; t += 256)
            xs[el][t * XSTR + DIN] = (_Float16)0.0f;
    }
    for (int j = tid; j < 16 * 128; j += 256) b2B[j] = (_Float16)0.0f;

    // ---------------- A-fragments (weights, resident in registers) ----------------
    // A[m=lane&15][k=q*8+j] ; layer-1 A = Whh0 (K=64), layer-2 A = [Wih1 | Whh1] (K=128)
    f16x8 a1[4][2];
    f16x8 a2[4][4];
    #pragma unroll
    for (int mt = 0; mt < 4; ++mt) {
        const int g = 64 * w + 16 * mt + m;
        #pragma unroll
        for (int kt = 0; kt < 2; ++kt) {
            const float* p = Whh0 + g * H + kt * 32 + q * 8;
            f16x8 f;
            #pragma unroll
            for (int j = 0; j < 8; ++j) f[j] = (_Float16)p[j];
            a1[mt][kt] = f;
        }
        #pragma unroll
        for (int kt = 0; kt < 2; ++kt) {
            const float* p = Wih1 + g * H + kt * 32 + q * 8;
            f16x8 f;
            #pragma unroll
            for (int j = 0; j < 8; ++j) f[j] = (_Float16)p[j];
            a2[mt][kt] = f;
        }
        #pragma unroll
        for (int kt = 0; kt < 2; ++kt) {
            const float* p = Whh1 + g * H + kt * 32 + q * 8;
            f16x8 f;
            #pragma unroll
            for (int j = 0; j < 8; ++j) f[j] = (_Float16)p[j];
            a2[mt][2 + kt] = f;
        }
    }

    // ---------------- G-phase weights: Wih0 rows {hu,64+hu,128+hu,192+hu} ----------------
    half2v w0x[4][3];
    float  bias0g[4], bias1g[4];
    #pragma unroll
    for (int gt = 0; gt < 4; ++gt) {
        const int g = gt * 64 + hu;
        const float* r = Wih0 + g * DIN;
        w0x[gt][0] = half2v{(_Float16)r[0], (_Float16)r[1]};
        w0x[gt][1] = half2v{(_Float16)r[2], (_Float16)r[3]};
        w0x[gt][2] = half2v{(_Float16)r[4], (_Float16)0.0f};
        bias0g[gt] = bih0[g] + bhh0[g];
        bias1g[gt] = bih1[g] + bhh1[g];
    }

    float c1 = 0.0f, c2 = 0.0f, h2fin = 0.0f;
    const f32x4 zz = {0.0f, 0.0f, 0.0f, 0.0f};
    const int ge = w & 1;              // elem owned in G phase

    __syncthreads();

    // ================= main loop: iteration i does layer2(t=i-1) + layer1(t=i) =================
    #pragma unroll 1
    for (int i = 0; i <= TSEQ; ++i) {
        // ---- M phase: B-fragments + 24 mfma + raw writeback ----
        f16x8 bf[4];
        #pragma unroll
        for (int kt = 0; kt < 4; ++kt)
            bf[kt] = *(const f16x8*)&b2B[b2idx(m, kt * 32 + q * 8)];

        f32x4 d1[4], d2[4];
        #pragma unroll
        for (int mt = 0; mt < 4; ++mt) {
            d1[mt] = __builtin_amdgcn_mfma_f32_16x16x32_f16(a1[mt][0], bf[0], zz, 0, 0, 0);
            d1[mt] = __builtin_amdgcn_mfma_f32_16x16x32_f16(a1[mt][1], bf[1], d1[mt], 0, 0, 0);
            d2[mt] = __builtin_amdgcn_mfma_f32_16x16x32_f16(a2[mt][0], bf[0], zz, 0, 0, 0);
            #pragma unroll
            for (int kt = 1; kt < 4; ++kt)
                d2[mt] = __builtin_amdgcn_mfma_f32_16x16x32_f16(a2[mt][kt], bf[kt], d2[mt], 0, 0, 0);
        }
        if (m < BT) {   // D col = lane&15 = elem; rows 16mt+4q+reg contiguous -> b128 stores
            #pragma unroll
            for (int mt = 0; mt < 4; ++mt) {
                *(f32x4*)&raw1[(64 * w + 16 * mt + 4 * q) + m * RAWSTR] = d1[mt];
                *(f32x4*)&raw2[(64 * w + 16 * mt + 4 * q) + m * RAWSTR] = d2[mt];
            }
        }
        __syncthreads();

        // ---- G phase: wave-specialized ----
        if (w < 2) {
            // layer-1 update for t=i, elem ge
            if (i < TSEQ) {
                const half2v* xv = (const half2v*)&xs[ge][i * XSTR];
                half2v xa = xv[0], xb = xv[1], xc = xv[2];
                float p0 = FDOT2(xc, w0x[0][2], FDOT2(xb, w0x[0][1], FDOT2(xa, w0x[0][0], bias0g[0])));
                float p1 = FDOT2(xc, w0x[1][2], FDOT2(xb, w0x[1][1], FDOT2(xa, w0x[1][0], bias0g[1])));
                float p2 = FDOT2(xc, w0x[2][2], FDOT2(xb, w0x[2][1], FDOT2(xa, w0x[2][0], bias0g[2])));
                float p3 = FDOT2(xc, w0x[3][2], FDOT2(xb, w0x[3][1], FDOT2(xa, w0x[3][0], bias0g[3])));
                p0 += raw1[hu       + ge * RAWSTR];
                p1 += raw1[64 + hu  + ge * RAWSTR];
                p2 += raw1[128 + hu + ge * RAWSTR];
                p3 += raw1[192 + hu + ge * RAWSTR];
                float iv = sigmoid_fast(p0);
                float fv = sigmoid_fast(p1);
                float gv = tanh_fast(p2);
                float ov = sigmoid_fast(p3);
                c1 = fmaf(fv, c1, iv * gv);
                b2B[b2idx(ge, hu)] = (_Float16)(ov * tanh_fast(c1));
            }
        } else {
            // layer-2 update for t=i-1, elem ge
            if (i > 0) {
                float q0 = bias1g[0] + raw2[hu       + ge * RAWSTR];
                float q1 = bias1g[1] + raw2[64 + hu  + ge * RAWSTR];
                float q2 = bias1g[2] + raw2[128 + hu + ge * RAWSTR];
                float q3 = bias1g[3] + raw2[192 + hu + ge * RAWSTR];
                float iv = sigmoid_fast(q0);
                float fv = sigmoid_fast(q1);
                float gv = tanh_fast(q2);
                float ov = sigmoid_fast(q3);
                c2 = fmaf(fv, c2, iv * gv);
                h2fin = ov * tanh_fast(c2);
                b2B[b2idx(ge, 64 + hu)] = (_Float16)h2fin;
            }
        }
        __syncthreads();
    }

    // ---------------- epilogue: out = relu(h2(T-1) @ Wfc^T + bfc) ----------------
    if (w >= 2) h2f[ge][hu] = h2fin;   // h2 lives in waves 2-3
    __syncthreads();
    {
        const int e = tid >> 7;          // 0 or 1
        const int o = tid & (NOUT - 1);  // 0..127
        const float4* wr = (const float4*)(Wfc + o * H);
        const float*  hv = h2f[e];
        float s0 = 0.0f, s1 = 0.0f, s2 = 0.0f, s3 = 0.0f;
        #pragma unroll
        for (int k = 0; k < H / 4; ++k) {
            float4 wv = wr[k];
            s0 = fmaf(wv.x, hv[4 * k + 0], s0);
            s1 = fmaf(wv.y, hv[4 * k + 1], s1);
            s2 = fmaf(wv.z, hv[4 * k + 2], s2);
            s3 = fmaf(wv.w, hv[4 * k + 3], s3);
        }
        float acc = bfc[o] + (s0 + s1) + (s2 + s3);
        out[(size_t)(b0 + e) * NOUT + o] = fmaxf(acc, 0.0f);
    }
}

extern "C" void kernel_launch(void* const* d_in, const int* in_sizes, int n_in,
                              void* d_out, int out_size, void* d_ws, size_t ws_size,
                              hipStream_t stream) {
    const float* x    = (const float*)d_in[0];
    const float* Wih0 = (const float*)d_in[1];
    const float* Whh0 = (const float*)d_in[2];
    const float* bih0 = (const float*)d_in[3];
    const float* bhh0 = (const float*)d_in[4];
    const float* Wih1 = (const float*)d_in[5];
    const float* Whh1 = (const float*)d_in[6];
    const float* bih1 = (const float*)d_in[7];
    const float* bhh1 = (const float*)d_in[8];
    const float* Wfc  = (const float*)d_in[9];
    const float* bfc  = (const float*)d_in[10];
    float* out = (float*)d_out;

    lstm_mfma<<<dim3(BATCH / BT), dim3(256), 0, stream>>>(
        x, Wih0, Whh0, bih0, bhh0, Wih1, Whh1, bih1, bhh1, Wfc, bfc, out);
}